// Round 1
// baseline (5045.974 us; speedup 1.0000x reference)
//
#include <hip/hip_runtime.h>
#include <hip/hip_bf16.h>
#include <math.h>

// Problem constants
#define NN 116          // nodes
#define NE 1160         // edges
#define CCH 256         // channels after conv
#define FF 653          // feature dim (conv output length / SAGE dim)
#define CF (CCH*FF)     // 167168 floats per node
#define CF4 (CF/4)      // 41792 float4 per node
#define MM (NN*CCH)     // 29696 GEMM rows
#define SZ_H ((size_t)NN*CF)  // 19391488 floats per h buffer

// ---------------------------------------------------------------------------
// CSR build: per-dst incoming edge source lists. edge_index int32 [2][NE].
__global__ void build_csr_k(const int* __restrict__ ei, int* __restrict__ off,
                            int* __restrict__ lst) {
    __shared__ int s_cnt[NN];
    __shared__ int s_off[NN + 1];
    int t = threadIdx.x;
    for (int i = t; i < NN; i += blockDim.x) s_cnt[i] = 0;
    __syncthreads();
    for (int e = t; e < NE; e += blockDim.x) atomicAdd(&s_cnt[ei[NE + e]], 1);
    __syncthreads();
    if (t == 0) {
        s_off[0] = 0;
        for (int i = 0; i < NN; ++i) s_off[i + 1] = s_off[i] + s_cnt[i];
    }
    __syncthreads();
    for (int i = t; i < NN; i += blockDim.x) { off[i] = s_off[i]; s_cnt[i] = 0; }
    if (t == 0) off[NN] = s_off[NN];
    __syncthreads();
    for (int e = t; e < NE; e += blockDim.x) {
        int d = ei[NE + e];
        int p = atomicAdd(&s_cnt[d], 1);
        lst[s_off[d] + p] = ei[e];   // src node
    }
}

// ---------------------------------------------------------------------------
// Grouped Conv1d: x[116,64,657] -> h[116,256,653], w[256,16,5], groups=4
__global__ void conv1d_k(const float* __restrict__ x, const float* __restrict__ w,
                         const float* __restrict__ b, float* __restrict__ h) {
    int idx = blockIdx.x * 256 + threadIdx.x;
    const int total = NN * CCH * FF;
    if (idx >= total) return;
    int f  = idx % FF;
    int no = idx / FF;
    int o  = no % CCH;
    int n  = no / CCH;
    int g  = o >> 6;                       // group (0..3)
    const float* xp = x + ((size_t)n * 64 + g * 16) * 657 + f;
    const float* wp = w + o * 80;
    float acc = b[o];
#pragma unroll
    for (int i = 0; i < 16; ++i) {
#pragma unroll
        for (int k = 0; k < 5; ++k)
            acc = fmaf(xp[i * 657 + k], wp[i * 5 + k], acc);
    }
    h[idx] = acc;
}

// ---------------------------------------------------------------------------
// Segment max over incoming edges; empty segment -> 0. Flat float4 per node.
__global__ void seg_max_k(const float* __restrict__ h, float* __restrict__ agg,
                          const int* __restrict__ off, const int* __restrict__ lst) {
    int j = blockIdx.x * 256 + threadIdx.x;
    if (j >= CF4) return;
    int n  = blockIdx.y;
    int o0 = off[n], o1 = off[n + 1];
    float4 m = make_float4(0.f, 0.f, 0.f, 0.f);
    if (o1 > o0) {
        m = make_float4(-3.4e38f, -3.4e38f, -3.4e38f, -3.4e38f);
        for (int e = o0; e < o1; ++e) {
            const float4 v = ((const float4*)(h + (size_t)lst[e] * CF))[j];
            m.x = fmaxf(m.x, v.x); m.y = fmaxf(m.y, v.y);
            m.z = fmaxf(m.z, v.z); m.w = fmaxf(m.w, v.w);
        }
    }
    ((float4*)(agg + (size_t)n * CF))[j] = m;
}

// ---------------------------------------------------------------------------
// out[m,g] = sum_f agg[m,f]*wl[g,f] + sum_f h[m,f]*wr[g,f] + bias[g]
// M=29696 (div by 128), N=653 (guarded), K=653 (guarded). fp32 tiled.
__global__ __launch_bounds__(256) void sage_gemm_k(
    const float* __restrict__ Aagg, const float* __restrict__ Ah,
    const float* __restrict__ Wl,   const float* __restrict__ Wr,
    const float* __restrict__ bias, float* __restrict__ Cout) {
    __shared__ float As[16][132];   // [k][m], padded: stride 132 (16B-aligned rows)
    __shared__ float Bs[16][68];    // [k][g]
    const int bm  = blockIdx.x * 128;
    const int bn  = blockIdx.y * 64;
    const int tid = threadIdx.x;
    const int tx  = tid & 15;       // col group: cols bn + tx*4 .. +3
    const int ty  = tid >> 4;       // row group: rows bm + ty*8 .. +7
    float acc[8][4];
#pragma unroll
    for (int i = 0; i < 8; ++i)
#pragma unroll
        for (int j = 0; j < 4; ++j) acc[i][j] = 0.f;

    for (int pass = 0; pass < 2; ++pass) {
        const float* A = pass ? Ah : Aagg;
        const float* W = pass ? Wr : Wl;
        for (int k0 = 0; k0 < FF; k0 += 16) {
            // A tile [128 rows][16 k] -> As[k][r]
#pragma unroll
            for (int i = 0; i < 8; ++i) {
                int e = i * 256 + tid;
                int r = e >> 4, kk = e & 15;
                int gk = k0 + kk;
                float v = (gk < FF) ? A[(size_t)(bm + r) * FF + gk] : 0.f;
                As[kk][r] = v;
            }
            // B tile: W[g,f]; [64 g][16 k] -> Bs[k][g]
#pragma unroll
            for (int i = 0; i < 4; ++i) {
                int e = i * 256 + tid;
                int g = e >> 4, kk = e & 15;
                int gk = k0 + kk, gg = bn + g;
                float v = (gg < FF && gk < FF) ? W[(size_t)gg * FF + gk] : 0.f;
                Bs[kk][g] = v;
            }
            __syncthreads();
#pragma unroll
            for (int kk = 0; kk < 16; ++kk) {
                float4 a0 = *(const float4*)&As[kk][ty * 8];
                float4 a1 = *(const float4*)&As[kk][ty * 8 + 4];
                float4 bv = *(const float4*)&Bs[kk][tx * 4];
                float a[8] = {a0.x, a0.y, a0.z, a0.w, a1.x, a1.y, a1.z, a1.w};
                float bb[4] = {bv.x, bv.y, bv.z, bv.w};
#pragma unroll
                for (int i = 0; i < 8; ++i)
#pragma unroll
                    for (int j = 0; j < 4; ++j)
                        acc[i][j] = fmaf(a[i], bb[j], acc[i][j]);
            }
            __syncthreads();
        }
    }
#pragma unroll
    for (int j = 0; j < 4; ++j) {
        int g = bn + tx * 4 + j;
        if (g >= FF) continue;
        float bval = bias[g];
#pragma unroll
        for (int i = 0; i < 8; ++i) {
            int m = bm + ty * 8 + i;
            Cout[(size_t)m * FF + g] = acc[i][j] + bval;
        }
    }
}

// ---------------------------------------------------------------------------
// Mean over nodes: pool[c,f] = mean_n h[n,c,f]
__global__ void pool_k(const float* __restrict__ h, float* __restrict__ pool) {
    int j = blockIdx.x * 256 + threadIdx.x;
    if (j >= CF4) return;
    float4 s = make_float4(0.f, 0.f, 0.f, 0.f);
    for (int n = 0; n < NN; ++n) {
        const float4 v = ((const float4*)(h + (size_t)n * CF))[j];
        s.x += v.x; s.y += v.y; s.z += v.z; s.w += v.w;
    }
    const float inv = 1.0f / NN;
    s.x *= inv; s.y *= inv; s.z *= inv; s.w *= inv;
    ((float4*)pool)[j] = s;
}

// ---------------------------------------------------------------------------
// Head: per channel-row c: fc1(653->128)+GELU, fc2(128->32)+GELU, fc3(32->4),
// softmax over the 4. One block per row, 128 threads.
__device__ __forceinline__ float gelu_exact(float v) {
    return 0.5f * v * (1.0f + erff(v * 0.70710678118654752f));
}

__global__ void head_k(const float* __restrict__ pool,
                       const float* __restrict__ w1, const float* __restrict__ b1,
                       const float* __restrict__ w2, const float* __restrict__ b2,
                       const float* __restrict__ w3, const float* __restrict__ b3,
                       float* __restrict__ out) {
    __shared__ float row[FF];
    __shared__ float h1[128];
    __shared__ float h2[32];
    __shared__ float sc[4];
    const int c = blockIdx.x;
    const int t = threadIdx.x;
    for (int i = t; i < FF; i += 128) row[i] = pool[(size_t)c * FF + i];
    __syncthreads();
    {   // fc1 + gelu
        const float* wp = w1 + (size_t)t * FF;
        float s = b1[t];
        for (int i = 0; i < FF; ++i) s = fmaf(row[i], wp[i], s);
        h1[t] = gelu_exact(s);
    }
    __syncthreads();
    if (t < 32) {   // fc2 + gelu
        const float* wp = w2 + (size_t)t * 128;
        float s = b2[t];
#pragma unroll
        for (int i = 0; i < 128; ++i) s = fmaf(h1[i], wp[i], s);
        h2[t] = gelu_exact(s);
    }
    __syncthreads();
    if (t < 4) {    // fc3
        const float* wp = w3 + (size_t)t * 32;
        float s = b3[t];
#pragma unroll
        for (int i = 0; i < 32; ++i) s = fmaf(h2[i], wp[i], s);
        sc[t] = s;
    }
    __syncthreads();
    if (t < 4) {    // softmax over 4
        float mx = fmaxf(fmaxf(sc[0], sc[1]), fmaxf(sc[2], sc[3]));
        float e0 = __expf(sc[0] - mx), e1 = __expf(sc[1] - mx);
        float e2 = __expf(sc[2] - mx), e3 = __expf(sc[3] - mx);
        float inv = 1.0f / (e0 + e1 + e2 + e3);
        float ev = (t == 0) ? e0 : (t == 1) ? e1 : (t == 2) ? e2 : e3;
        out[(size_t)c * 4 + t] = ev * inv;
    }
}

// ---------------------------------------------------------------------------
extern "C" void kernel_launch(void* const* d_in, const int* in_sizes, int n_in,
                              void* d_out, int out_size, void* d_ws, size_t ws_size,
                              hipStream_t stream) {
    const float* x      = (const float*)d_in[0];
    const int*   ei     = (const int*)  d_in[1];
    const float* conv_w = (const float*)d_in[2];
    const float* conv_b = (const float*)d_in[3];
    const float* wl     = (const float*)d_in[4];
    const float* wr     = (const float*)d_in[5];
    const float* sb     = (const float*)d_in[6];
    const float* fc1w   = (const float*)d_in[7];
    const float* fc1b   = (const float*)d_in[8];
    const float* fc2w   = (const float*)d_in[9];
    const float* fc2b   = (const float*)d_in[10];
    const float* fc3w   = (const float*)d_in[11];
    const float* fc3b   = (const float*)d_in[12];
    float* out = (float*)d_out;

    float* hA   = (float*)d_ws;
    float* hB   = hA + SZ_H;
    float* agg  = hB + SZ_H;
    float* pool = agg + SZ_H;
    int*   off  = (int*)(pool + CF);
    int*   lst  = off + 128;

    build_csr_k<<<1, 256, 0, stream>>>(ei, off, lst);

    {
        const int total = NN * CCH * FF;
        conv1d_k<<<(total + 255) / 256, 256, 0, stream>>>(x, conv_w, conv_b, hA);
    }

    dim3 sg_grid((CF4 + 255) / 256, NN);
    dim3 gm_grid(MM / 128, (FF + 63) / 64);
    float* cur = hA;
    float* nxt = hB;
    for (int layer = 0; layer < 3; ++layer) {
        seg_max_k<<<sg_grid, 256, 0, stream>>>(cur, agg, off, lst);
        sage_gemm_k<<<gm_grid, 256, 0, stream>>>(agg, cur, wl, wr, sb, nxt);
        float* tmp = cur; cur = nxt; nxt = tmp;
    }
    // after 3 layers result is in `cur`
    pool_k<<<(CF4 + 255) / 256, 256, 0, stream>>>(cur, pool);
    head_k<<<CCH, 128, 0, stream>>>(pool, fc1w, fc1b, fc2w, fc2b, fc3w, fc3b, out);
}

// Round 2
// 929.973 us; speedup vs baseline: 5.4259x; 5.4259x over previous
//
#include <hip/hip_runtime.h>
#include <hip/hip_bf16.h>
#include <math.h>

// Problem constants
#define NN 116           // nodes
#define NE 1160          // edges
#define CCH 256          // channels after conv
#define FF 653           // feature dim
#define KP 672           // padded feature stride (bf16), mult of 32
#define MM (NN*CCH)      // 29696 GEMM rows (= 232 * 128)
#define NPAD 768         // padded N for weight matrix (6 * 128)
#define SZH ((size_t)MM*KP)   // elems per bf16 h buffer

typedef unsigned short ushort;
typedef short bf16x8 __attribute__((ext_vector_type(8)));
typedef float f32x4 __attribute__((ext_vector_type(4)));

// ---- bf16 helpers (bit-level) ----------------------------------------------
__device__ __forceinline__ float bfbits_to_f(ushort u) {
    unsigned int w = ((unsigned int)u) << 16;
    return __uint_as_float(w);
}
__device__ __forceinline__ ushort f_to_bfbits(float f) {   // RTNE
    unsigned int u = __float_as_uint(f);
    u += 0x7FFFu + ((u >> 16) & 1u);
    return (ushort)(u >> 16);
}

__device__ __forceinline__ void gl_lds16(const void* g, void* l) {
    __builtin_amdgcn_global_load_lds(
        (const __attribute__((address_space(1))) unsigned int*)g,
        (__attribute__((address_space(3))) unsigned int*)l, 16, 0, 0);
}

// ---------------------------------------------------------------------------
// CSR build: per-dst incoming-edge source lists.
__global__ void build_csr_k(const int* __restrict__ ei, int* __restrict__ off,
                            int* __restrict__ lst) {
    __shared__ int s_cnt[NN];
    __shared__ int s_off[NN + 1];
    int t = threadIdx.x;
    for (int i = t; i < NN; i += blockDim.x) s_cnt[i] = 0;
    __syncthreads();
    for (int e = t; e < NE; e += blockDim.x) atomicAdd(&s_cnt[ei[NE + e]], 1);
    __syncthreads();
    if (t == 0) {
        s_off[0] = 0;
        for (int i = 0; i < NN; ++i) s_off[i + 1] = s_off[i] + s_cnt[i];
    }
    __syncthreads();
    for (int i = t; i < NN; i += blockDim.x) { off[i] = s_off[i]; s_cnt[i] = 0; }
    if (t == 0) off[NN] = s_off[NN];
    __syncthreads();
    for (int e = t; e < NE; e += blockDim.x) {
        int d = ei[NE + e];
        int p = atomicAdd(&s_cnt[d], 1);
        lst[s_off[d] + p] = ei[e];
    }
}

// ---------------------------------------------------------------------------
// Quantize + concat weights: Wc[2][NPAD][KP] bf16; pass0=Wl, pass1=Wr, zero pad.
__global__ void build_wc_k(const float* __restrict__ wl, const float* __restrict__ wr,
                           ushort* __restrict__ wc) {
    int idx = blockIdx.x * 256 + threadIdx.x;
    const int total = 2 * NPAD * KP;
    if (idx >= total) return;
    int k = idx % KP;
    int rem = idx / KP;
    int n = rem % NPAD;
    int p = rem / NPAD;
    float v = 0.f;
    if (n < FF && k < FF) v = (p ? wr : wl)[(size_t)n * FF + k];
    wc[idx] = f_to_bfbits(v);
}

// ---------------------------------------------------------------------------
// Grouped Conv1d -> bf16 h [MM][KP], zero pads.
__global__ void conv1d_k(const float* __restrict__ x, const float* __restrict__ w,
                         const float* __restrict__ b, ushort* __restrict__ h) {
    int idx = blockIdx.x * 256 + threadIdx.x;
    const int total = MM * KP;
    if (idx >= total) return;
    int f  = idx % KP;
    int no = idx / KP;
    if (f >= FF) { h[idx] = 0; return; }
    int o  = no % CCH;
    int n  = no / CCH;
    int g  = o >> 6;
    const float* xp = x + ((size_t)n * 64 + g * 16) * 657 + f;
    const float* wp = w + o * 80;
    float acc = b[o];
#pragma unroll
    for (int i = 0; i < 16; ++i)
#pragma unroll
        for (int k = 0; k < 5; ++k)
            acc = fmaf(xp[i * 657 + k], wp[i * 5 + k], acc);
    h[idx] = f_to_bfbits(acc);
}

// ---------------------------------------------------------------------------
// Segment-max gather in bf16 domain. Per node n: agg row = max over src rows.
// Thread handles 8 contiguous bf16 (one uint4). 116 x 21504 threads.
__global__ void seg_max_k(const ushort* __restrict__ h, ushort* __restrict__ agg,
                          const int* __restrict__ off, const int* __restrict__ lst) {
    int j = blockIdx.x * 256 + threadIdx.x;   // 0..21503 = c*84 + chunk
    int c = j / 84;
    int chunk = j % 84;
    int n = blockIdx.y;
    int o0 = off[n], o1 = off[n + 1];
    size_t dsti = ((size_t)(n * CCH + c)) * KP + chunk * 8;
    if (o0 == o1) {
        *(uint4*)(agg + dsti) = make_uint4(0, 0, 0, 0);
        return;
    }
    float m[8];
#pragma unroll
    for (int i = 0; i < 8; ++i) m[i] = -3.4e38f;
    for (int e = o0; e < o1; ++e) {
        int s = lst[e];
        const uint4 v = *(const uint4*)(h + ((size_t)(s * CCH + c)) * KP + chunk * 8);
        unsigned int u[4] = {v.x, v.y, v.z, v.w};
#pragma unroll
        for (int q = 0; q < 4; ++q) {
            float lo = __uint_as_float(u[q] << 16);
            float hi = __uint_as_float(u[q] & 0xFFFF0000u);
            m[2*q]   = fmaxf(m[2*q],   lo);
            m[2*q+1] = fmaxf(m[2*q+1], hi);
        }
    }
    // results are exact bf16 values -> truncate bits
    unsigned int o[4];
#pragma unroll
    for (int q = 0; q < 4; ++q) {
        unsigned int a = __float_as_uint(m[2*q])   >> 16;
        unsigned int bq = __float_as_uint(m[2*q+1]) & 0xFFFF0000u;
        o[q] = a | bq;
    }
    *(uint4*)(agg + dsti) = make_uint4(o[0], o[1], o[2], o[3]);
}

// ---------------------------------------------------------------------------
// MFMA GEMM: Hnxt[m][n] = sum_k Agg[m][k]Wl[n][k] + sum_k Hcur[m][k]Wr[n][k] + b[n]
// 128x128 block tile, 4 waves (2x2 of 64x64), BK=32, m97-style staging.
__global__ __launch_bounds__(256) void sage_gemm_k(
    const ushort* __restrict__ Agg, const ushort* __restrict__ Hcur,
    const ushort* __restrict__ Wc, const float* __restrict__ bias,
    ushort* __restrict__ Hnxt)
{
    __shared__ ushort As[128 * 32];
    __shared__ ushort Bs[128 * 32];
    const int tid  = threadIdx.x;
    const int lane = tid & 63;
    const int wid  = tid >> 6;
    const int bm = blockIdx.x * 128;
    const int bn = blockIdx.y * 128;
    const int wm = (wid >> 1) * 64;
    const int wn = (wid & 1) * 64;

    f32x4 acc[4][4];
#pragma unroll
    for (int i = 0; i < 4; ++i)
#pragma unroll
        for (int j = 0; j < 4; ++j) acc[i][j] = 0.f;

    const int srow = lane >> 2;     // 0..15 row within wave's 16-row band
    const int schk = (lane & 3) * 8;
    ushort* lA = As + wid * 16 * 32;
    ushort* lB = Bs + wid * 16 * 32;
    const int lr = lane & 15;
    const int kc = (lane >> 4) * 8;

    for (int pass = 0; pass < 2; ++pass) {
        const ushort* Ab = pass ? Hcur : Agg;
        const ushort* Wb = Wc + (size_t)pass * NPAD * KP;
        for (int k0 = 0; k0 < KP; k0 += 32) {
            const ushort* ga0 = Ab + (size_t)(bm + wid * 16 + srow) * KP + k0 + schk;
            const ushort* gb0 = Wb + (size_t)(bn + wid * 16 + srow) * KP + k0 + schk;
            gl_lds16(ga0, lA);
            gl_lds16(ga0 + (size_t)64 * KP, lA + 64 * 32);
            gl_lds16(gb0, lB);
            gl_lds16(gb0 + (size_t)64 * KP, lB + 64 * 32);
            __syncthreads();
            bf16x8 af[4], bfr[4];
#pragma unroll
            for (int i = 0; i < 4; ++i)
                af[i] = *(const bf16x8*)&As[(wm + i * 16 + lr) * 32 + kc];
#pragma unroll
            for (int j = 0; j < 4; ++j)
                bfr[j] = *(const bf16x8*)&Bs[(wn + j * 16 + lr) * 32 + kc];
#pragma unroll
            for (int i = 0; i < 4; ++i)
#pragma unroll
                for (int j = 0; j < 4; ++j)
                    acc[i][j] = __builtin_amdgcn_mfma_f32_16x16x32_bf16(
                        af[i], bfr[j], acc[i][j], 0, 0, 0);
            __syncthreads();
        }
    }
    // epilogue: C row = (lane>>4)*4 + reg, col = lane&15 (m89-verified mapping)
    const int lg = lane >> 4;
#pragma unroll
    for (int j = 0; j < 4; ++j) {
        int n = bn + wn + j * 16 + lr;
        if (n >= KP) continue;            // only cols < 672 exist in Hnxt
        bool valid = n < FF;
        float bv = valid ? bias[n] : 0.f;
#pragma unroll
        for (int i = 0; i < 4; ++i) {
#pragma unroll
            for (int r = 0; r < 4; ++r) {
                int m = bm + wm + i * 16 + lg * 4 + r;
                float v = valid ? (acc[i][j][r] + bv) : 0.f;
                Hnxt[(size_t)m * KP + n] = f_to_bfbits(v);
            }
        }
    }
}

// ---------------------------------------------------------------------------
// Mean over nodes: pool[c][f] fp32, from bf16 h.
__global__ void pool_k(const ushort* __restrict__ h, float* __restrict__ pool) {
    int j = blockIdx.x * 256 + threadIdx.x;   // c*84 + chunk
    if (j >= 256 * 84) return;
    int c = j / 84;
    int chunk = j % 84;
    float s[8];
#pragma unroll
    for (int i = 0; i < 8; ++i) s[i] = 0.f;
    for (int n = 0; n < NN; ++n) {
        const uint4 v = *(const uint4*)(h + ((size_t)(n * CCH + c)) * KP + chunk * 8);
        unsigned int u[4] = {v.x, v.y, v.z, v.w};
#pragma unroll
        for (int q = 0; q < 4; ++q) {
            s[2*q]   += __uint_as_float(u[q] << 16);
            s[2*q+1] += __uint_as_float(u[q] & 0xFFFF0000u);
        }
    }
    const float inv = 1.0f / NN;
    float* dst = pool + (size_t)c * KP + chunk * 8;
#pragma unroll
    for (int i = 0; i < 8; ++i) dst[i] = s[i] * inv;
}

// ---------------------------------------------------------------------------
__device__ __forceinline__ float gelu_exact(float v) {
    return 0.5f * v * (1.0f + erff(v * 0.70710678118654752f));
}

__global__ void head_k(const float* __restrict__ pool,
                       const float* __restrict__ w1, const float* __restrict__ b1,
                       const float* __restrict__ w2, const float* __restrict__ b2,
                       const float* __restrict__ w3, const float* __restrict__ b3,
                       float* __restrict__ out) {
    __shared__ float row[FF];
    __shared__ float h1[128];
    __shared__ float h2[32];
    __shared__ float sc[4];
    const int c = blockIdx.x;
    const int t = threadIdx.x;
    for (int i = t; i < FF; i += 128) row[i] = pool[(size_t)c * KP + i];
    __syncthreads();
    {
        const float* wp = w1 + (size_t)t * FF;
        float s = b1[t];
        for (int i = 0; i < FF; ++i) s = fmaf(row[i], wp[i], s);
        h1[t] = gelu_exact(s);
    }
    __syncthreads();
    if (t < 32) {
        const float* wp = w2 + (size_t)t * 128;
        float s = b2[t];
#pragma unroll
        for (int i = 0; i < 128; ++i) s = fmaf(h1[i], wp[i], s);
        h2[t] = gelu_exact(s);
    }
    __syncthreads();
    if (t < 4) {
        const float* wp = w3 + (size_t)t * 32;
        float s = b3[t];
#pragma unroll
        for (int i = 0; i < 32; ++i) s = fmaf(h2[i], wp[i], s);
        sc[t] = s;
    }
    __syncthreads();
    if (t < 4) {
        float mx = fmaxf(fmaxf(sc[0], sc[1]), fmaxf(sc[2], sc[3]));
        float e0 = __expf(sc[0] - mx), e1 = __expf(sc[1] - mx);
        float e2 = __expf(sc[2] - mx), e3 = __expf(sc[3] - mx);
        float inv = 1.0f / (e0 + e1 + e2 + e3);
        float ev = (t == 0) ? e0 : (t == 1) ? e1 : (t == 2) ? e2 : e3;
        out[(size_t)c * 4 + t] = ev * inv;
    }
}

// ---------------------------------------------------------------------------
extern "C" void kernel_launch(void* const* d_in, const int* in_sizes, int n_in,
                              void* d_out, int out_size, void* d_ws, size_t ws_size,
                              hipStream_t stream) {
    const float* x      = (const float*)d_in[0];
    const int*   ei     = (const int*)  d_in[1];
    const float* conv_w = (const float*)d_in[2];
    const float* conv_b = (const float*)d_in[3];
    const float* wl     = (const float*)d_in[4];
    const float* wr     = (const float*)d_in[5];
    const float* sb     = (const float*)d_in[6];
    const float* fc1w   = (const float*)d_in[7];
    const float* fc1b   = (const float*)d_in[8];
    const float* fc2w   = (const float*)d_in[9];
    const float* fc2b   = (const float*)d_in[10];
    const float* fc3w   = (const float*)d_in[11];
    const float* fc3b   = (const float*)d_in[12];
    float* out = (float*)d_out;

    ushort* hA  = (ushort*)d_ws;
    ushort* hB  = hA + SZH;
    ushort* agg = hB + SZH;
    ushort* wc  = agg + SZH;
    float*  pool = (float*)(wc + (size_t)2 * NPAD * KP);
    int*    off  = (int*)(pool + (size_t)CCH * KP);
    int*    lst  = off + 128;

    build_csr_k<<<1, 256, 0, stream>>>(ei, off, lst);
    build_wc_k<<<(2 * NPAD * KP + 255) / 256, 256, 0, stream>>>(wl, wr, wc);
    conv1d_k<<<((int)(MM * KP) + 255) / 256, 256, 0, stream>>>(x, conv_w, conv_b, hA);

    dim3 sg_grid(84, NN);
    dim3 gm_grid(MM / 128, NPAD / 128);
    ushort* cur = hA;
    ushort* nxt = hB;
    for (int layer = 0; layer < 3; ++layer) {
        seg_max_k<<<sg_grid, 256, 0, stream>>>(cur, agg, off, lst);
        sage_gemm_k<<<gm_grid, 256, 0, stream>>>(agg, cur, wc, sb, nxt);
        ushort* tmp = cur; cur = nxt; nxt = tmp;
    }
    pool_k<<<84, 256, 0, stream>>>(cur, pool);
    head_k<<<CCH, 128, 0, stream>>>(pool, fc1w, fc1b, fc2w, fc2b, fc3w, fc3b, out);
}

// Round 3
// 695.347 us; speedup vs baseline: 7.2568x; 1.3374x over previous
//
#include <hip/hip_runtime.h>
#include <hip/hip_bf16.h>
#include <math.h>

// Problem constants
#define NN 116           // nodes
#define NE 1160          // edges
#define CCH 256          // channels after conv
#define FF 653           // feature dim
#define KP 672           // padded feature stride (bf16), mult of 32
#define MM (NN*CCH)      // 29696 GEMM rows (= 232 * 128)
#define NPAD 768         // padded N for weight matrix (6 * 128)
#define SZH ((size_t)MM*KP)   // elems per bf16 h buffer

typedef unsigned short ushort;
typedef short bf16x8 __attribute__((ext_vector_type(8)));
typedef float f32x4 __attribute__((ext_vector_type(4)));

// ---- bf16 helpers (bit-level) ----------------------------------------------
__device__ __forceinline__ float bfbits_to_f(ushort u) {
    unsigned int w = ((unsigned int)u) << 16;
    return __uint_as_float(w);
}
__device__ __forceinline__ ushort f_to_bfbits(float f) {   // RTNE
    unsigned int u = __float_as_uint(f);
    u += 0x7FFFu + ((u >> 16) & 1u);
    return (ushort)(u >> 16);
}

__device__ __forceinline__ void gl_lds16(const void* g, void* l) {
    __builtin_amdgcn_global_load_lds(
        (const __attribute__((address_space(1))) unsigned int*)g,
        (__attribute__((address_space(3))) unsigned int*)l, 16, 0, 0);
}

// ---------------------------------------------------------------------------
// CSR build: per-dst incoming-edge source lists.
__global__ void build_csr_k(const int* __restrict__ ei, int* __restrict__ off,
                            int* __restrict__ lst) {
    __shared__ int s_cnt[NN];
    __shared__ int s_off[NN + 1];
    int t = threadIdx.x;
    for (int i = t; i < NN; i += blockDim.x) s_cnt[i] = 0;
    __syncthreads();
    for (int e = t; e < NE; e += blockDim.x) atomicAdd(&s_cnt[ei[NE + e]], 1);
    __syncthreads();
    if (t == 0) {
        s_off[0] = 0;
        for (int i = 0; i < NN; ++i) s_off[i + 1] = s_off[i] + s_cnt[i];
    }
    __syncthreads();
    for (int i = t; i < NN; i += blockDim.x) { off[i] = s_off[i]; s_cnt[i] = 0; }
    if (t == 0) off[NN] = s_off[NN];
    __syncthreads();
    for (int e = t; e < NE; e += blockDim.x) {
        int d = ei[NE + e];
        int p = atomicAdd(&s_cnt[d], 1);
        lst[s_off[d] + p] = ei[e];
    }
}

// ---------------------------------------------------------------------------
// Quantize + concat weights: Wc[2][NPAD][KP] bf16; pass0=Wl, pass1=Wr, zero pad.
__global__ void build_wc_k(const float* __restrict__ wl, const float* __restrict__ wr,
                           ushort* __restrict__ wc) {
    int idx = blockIdx.x * 256 + threadIdx.x;
    const int total = 2 * NPAD * KP;
    if (idx >= total) return;
    int k = idx % KP;
    int rem = idx / KP;
    int n = rem % NPAD;
    int p = rem / NPAD;
    float v = 0.f;
    if (n < FF && k < FF) v = (p ? wr : wl)[(size_t)n * FF + k];
    wc[idx] = f_to_bfbits(v);
}

// ---------------------------------------------------------------------------
// Grouped Conv1d -> bf16 h [MM][KP], zero pads.
// One thread per f-position, handling 16 output channels (one quarter group).
// x values (16 in-ch x 5 taps = 80 floats) live in VGPRs, reused 16x.
// Weight/bias loads are wave-uniform -> scalar (SGPR) path.
__global__ __launch_bounds__(256) void conv1d_k(
    const float* __restrict__ x, const float* __restrict__ w,
    const float* __restrict__ b, ushort* __restrict__ h) {
    const int f  = blockIdx.x * 256 + threadIdx.x;   // 0..767
    if (f >= KP) return;
    const int n  = blockIdx.y;
    const int oc = blockIdx.z;        // o-chunk: o0 = oc*16
    const int o0 = oc * 16;
    const int g  = o0 >> 6;           // group
    if (f >= FF) {                    // zero-pad band f in [653, 672)
#pragma unroll
        for (int oo = 0; oo < 16; ++oo)
            h[(size_t)(n * CCH + o0 + oo) * KP + f] = 0;
        return;
    }
    // load x window into registers
    float xv[16][5];
    const float* xp = x + ((size_t)n * 64 + g * 16) * 657 + f;
#pragma unroll
    for (int i = 0; i < 16; ++i)
#pragma unroll
        for (int k = 0; k < 5; ++k)
            xv[i][k] = xp[i * 657 + k];
    // 16 output channels
#pragma unroll
    for (int oo = 0; oo < 16; ++oo) {
        const int o = o0 + oo;
        const float* wp = w + o * 80;   // uniform address -> s_load
        float acc = b[o];
#pragma unroll
        for (int i = 0; i < 16; ++i)
#pragma unroll
            for (int k = 0; k < 5; ++k)
                acc = fmaf(xv[i][k], wp[i * 5 + k], acc);
        h[(size_t)(n * CCH + o) * KP + f] = f_to_bfbits(acc);
    }
}

// ---------------------------------------------------------------------------
// Segment-max gather in bf16 domain. Per node n: agg row = max over src rows.
// Thread handles 8 contiguous bf16 (one uint4). 116 x 21504 threads.
__global__ void seg_max_k(const ushort* __restrict__ h, ushort* __restrict__ agg,
                          const int* __restrict__ off, const int* __restrict__ lst) {
    int j = blockIdx.x * 256 + threadIdx.x;   // 0..21503 = c*84 + chunk
    int c = j / 84;
    int chunk = j % 84;
    int n = blockIdx.y;
    int o0 = off[n], o1 = off[n + 1];
    size_t dsti = ((size_t)(n * CCH + c)) * KP + chunk * 8;
    if (o0 == o1) {
        *(uint4*)(agg + dsti) = make_uint4(0, 0, 0, 0);
        return;
    }
    float m[8];
#pragma unroll
    for (int i = 0; i < 8; ++i) m[i] = -3.4e38f;
    for (int e = o0; e < o1; ++e) {
        int s = lst[e];
        const uint4 v = *(const uint4*)(h + ((size_t)(s * CCH + c)) * KP + chunk * 8);
        unsigned int u[4] = {v.x, v.y, v.z, v.w};
#pragma unroll
        for (int q = 0; q < 4; ++q) {
            float lo = __uint_as_float(u[q] << 16);
            float hi = __uint_as_float(u[q] & 0xFFFF0000u);
            m[2*q]   = fmaxf(m[2*q],   lo);
            m[2*q+1] = fmaxf(m[2*q+1], hi);
        }
    }
    unsigned int o[4];
#pragma unroll
    for (int q = 0; q < 4; ++q) {
        unsigned int a = __float_as_uint(m[2*q])   >> 16;
        unsigned int bq = __float_as_uint(m[2*q+1]) & 0xFFFF0000u;
        o[q] = a | bq;
    }
    *(uint4*)(agg + dsti) = make_uint4(o[0], o[1], o[2], o[3]);
}

// ---------------------------------------------------------------------------
// MFMA GEMM: Hnxt[m][n] = sum_k Agg[m][k]Wl[n][k] + sum_k Hcur[m][k]Wr[n][k] + b[n]
// 128x128 block tile, 4 waves (2x2 of 64x64), BK=32, m97-style staging.
__global__ __launch_bounds__(256) void sage_gemm_k(
    const ushort* __restrict__ Agg, const ushort* __restrict__ Hcur,
    const ushort* __restrict__ Wc, const float* __restrict__ bias,
    ushort* __restrict__ Hnxt)
{
    __shared__ ushort As[128 * 32];
    __shared__ ushort Bs[128 * 32];
    const int tid  = threadIdx.x;
    const int lane = tid & 63;
    const int wid  = tid >> 6;
    const int bm = blockIdx.x * 128;
    const int bn = blockIdx.y * 128;
    const int wm = (wid >> 1) * 64;
    const int wn = (wid & 1) * 64;

    f32x4 acc[4][4];
#pragma unroll
    for (int i = 0; i < 4; ++i)
#pragma unroll
        for (int j = 0; j < 4; ++j) acc[i][j] = 0.f;

    const int srow = lane >> 2;
    const int schk = (lane & 3) * 8;
    ushort* lA = As + wid * 16 * 32;
    ushort* lB = Bs + wid * 16 * 32;
    const int lr = lane & 15;
    const int kc = (lane >> 4) * 8;

    for (int pass = 0; pass < 2; ++pass) {
        const ushort* Ab = pass ? Hcur : Agg;
        const ushort* Wb = Wc + (size_t)pass * NPAD * KP;
        for (int k0 = 0; k0 < KP; k0 += 32) {
            const ushort* ga0 = Ab + (size_t)(bm + wid * 16 + srow) * KP + k0 + schk;
            const ushort* gb0 = Wb + (size_t)(bn + wid * 16 + srow) * KP + k0 + schk;
            gl_lds16(ga0, lA);
            gl_lds16(ga0 + (size_t)64 * KP, lA + 64 * 32);
            gl_lds16(gb0, lB);
            gl_lds16(gb0 + (size_t)64 * KP, lB + 64 * 32);
            __syncthreads();
            bf16x8 af[4], bfr[4];
#pragma unroll
            for (int i = 0; i < 4; ++i)
                af[i] = *(const bf16x8*)&As[(wm + i * 16 + lr) * 32 + kc];
#pragma unroll
            for (int j = 0; j < 4; ++j)
                bfr[j] = *(const bf16x8*)&Bs[(wn + j * 16 + lr) * 32 + kc];
#pragma unroll
            for (int i = 0; i < 4; ++i)
#pragma unroll
                for (int j = 0; j < 4; ++j)
                    acc[i][j] = __builtin_amdgcn_mfma_f32_16x16x32_bf16(
                        af[i], bfr[j], acc[i][j], 0, 0, 0);
            __syncthreads();
        }
    }
    const int lg = lane >> 4;
#pragma unroll
    for (int j = 0; j < 4; ++j) {
        int n = bn + wn + j * 16 + lr;
        if (n >= KP) continue;
        bool valid = n < FF;
        float bv = valid ? bias[n] : 0.f;
#pragma unroll
        for (int i = 0; i < 4; ++i) {
#pragma unroll
            for (int r = 0; r < 4; ++r) {
                int m = bm + wm + i * 16 + lg * 4 + r;
                float v = valid ? (acc[i][j][r] + bv) : 0.f;
                Hnxt[(size_t)m * KP + n] = f_to_bfbits(v);
            }
        }
    }
}

// ---------------------------------------------------------------------------
// Mean over nodes: pool[c][f] fp32, from bf16 h.
__global__ void pool_k(const ushort* __restrict__ h, float* __restrict__ pool) {
    int j = blockIdx.x * 256 + threadIdx.x;   // c*84 + chunk
    if (j >= 256 * 84) return;
    int c = j / 84;
    int chunk = j % 84;
    float s[8];
#pragma unroll
    for (int i = 0; i < 8; ++i) s[i] = 0.f;
    for (int n = 0; n < NN; ++n) {
        const uint4 v = *(const uint4*)(h + ((size_t)(n * CCH + c)) * KP + chunk * 8);
        unsigned int u[4] = {v.x, v.y, v.z, v.w};
#pragma unroll
        for (int q = 0; q < 4; ++q) {
            s[2*q]   += __uint_as_float(u[q] << 16);
            s[2*q+1] += __uint_as_float(u[q] & 0xFFFF0000u);
        }
    }
    const float inv = 1.0f / NN;
    float* dst = pool + (size_t)c * KP + chunk * 8;
#pragma unroll
    for (int i = 0; i < 8; ++i) dst[i] = s[i] * inv;
}

// ---------------------------------------------------------------------------
__device__ __forceinline__ float gelu_exact(float v) {
    return 0.5f * v * (1.0f + erff(v * 0.70710678118654752f));
}

__global__ void head_k(const float* __restrict__ pool,
                       const float* __restrict__ w1, const float* __restrict__ b1,
                       const float* __restrict__ w2, const float* __restrict__ b2,
                       const float* __restrict__ w3, const float* __restrict__ b3,
                       float* __restrict__ out) {
    __shared__ float row[FF];
    __shared__ float h1[128];
    __shared__ float h2[32];
    __shared__ float sc[4];
    const int c = blockIdx.x;
    const int t = threadIdx.x;
    for (int i = t; i < FF; i += 128) row[i] = pool[(size_t)c * KP + i];
    __syncthreads();
    {
        const float* wp = w1 + (size_t)t * FF;
        float s = b1[t];
        for (int i = 0; i < FF; ++i) s = fmaf(row[i], wp[i], s);
        h1[t] = gelu_exact(s);
    }
    __syncthreads();
    if (t < 32) {
        const float* wp = w2 + (size_t)t * 128;
        float s = b2[t];
#pragma unroll
        for (int i = 0; i < 128; ++i) s = fmaf(h1[i], wp[i], s);
        h2[t] = gelu_exact(s);
    }
    __syncthreads();
    if (t < 4) {
        const float* wp = w3 + (size_t)t * 32;
        float s = b3[t];
#pragma unroll
        for (int i = 0; i < 32; ++i) s = fmaf(h2[i], wp[i], s);
        sc[t] = s;
    }
    __syncthreads();
    if (t < 4) {
        float mx = fmaxf(fmaxf(sc[0], sc[1]), fmaxf(sc[2], sc[3]));
        float e0 = __expf(sc[0] - mx), e1 = __expf(sc[1] - mx);
        float e2 = __expf(sc[2] - mx), e3 = __expf(sc[3] - mx);
        float inv = 1.0f / (e0 + e1 + e2 + e3);
        float ev = (t == 0) ? e0 : (t == 1) ? e1 : (t == 2) ? e2 : e3;
        out[(size_t)c * 4 + t] = ev * inv;
    }
}

// ---------------------------------------------------------------------------
extern "C" void kernel_launch(void* const* d_in, const int* in_sizes, int n_in,
                              void* d_out, int out_size, void* d_ws, size_t ws_size,
                              hipStream_t stream) {
    const float* x      = (const float*)d_in[0];
    const int*   ei     = (const int*)  d_in[1];
    const float* conv_w = (const float*)d_in[2];
    const float* conv_b = (const float*)d_in[3];
    const float* wl     = (const float*)d_in[4];
    const float* wr     = (const float*)d_in[5];
    const float* sb     = (const float*)d_in[6];
    const float* fc1w   = (const float*)d_in[7];
    const float* fc1b   = (const float*)d_in[8];
    const float* fc2w   = (const float*)d_in[9];
    const float* fc2b   = (const float*)d_in[10];
    const float* fc3w   = (const float*)d_in[11];
    const float* fc3b   = (const float*)d_in[12];
    float* out = (float*)d_out;

    ushort* hA  = (ushort*)d_ws;
    ushort* hB  = hA + SZH;
    ushort* agg = hB + SZH;
    ushort* wc  = agg + SZH;
    float*  pool = (float*)(wc + (size_t)2 * NPAD * KP);
    int*    off  = (int*)(pool + (size_t)CCH * KP);
    int*    lst  = off + 128;

    build_csr_k<<<1, 256, 0, stream>>>(ei, off, lst);
    build_wc_k<<<(2 * NPAD * KP + 255) / 256, 256, 0, stream>>>(wl, wr, wc);
    {
        dim3 cgrid((KP + 255) / 256, NN, 16);
        conv1d_k<<<cgrid, 256, 0, stream>>>(x, conv_w, conv_b, hA);
    }

    dim3 sg_grid(84, NN);
    dim3 gm_grid(MM / 128, NPAD / 128);
    ushort* cur = hA;
    ushort* nxt = hB;
    for (int layer = 0; layer < 3; ++layer) {
        seg_max_k<<<sg_grid, 256, 0, stream>>>(cur, agg, off, lst);
        sage_gemm_k<<<gm_grid, 256, 0, stream>>>(agg, cur, wc, sb, nxt);
        ushort* tmp = cur; cur = nxt; nxt = tmp;
    }
    pool_k<<<84, 256, 0, stream>>>(cur, pool);
    head_k<<<CCH, 128, 0, stream>>>(pool, fc1w, fc1b, fc2w, fc2b, fc3w, fc3b, out);
}